// Round 11
// baseline (1859.096 us; speedup 1.0000x reference)
//
#include <hip/hip_runtime.h>
#include <hip/hip_bf16.h>
#include <stdint.h>
#include <stddef.h>

// ---------------- problem dims ----------------
#define NB 16
#define NS 256
#define NH 512
#define NE 256
#define NV 32000
#define NM (NB*NS)
#define N3H 1536

typedef __attribute__((ext_vector_type(8))) short short8v;
typedef __attribute__((ext_vector_type(4))) float float4v;
typedef __attribute__((address_space(1))) const unsigned int gas_u32;
typedef __attribute__((address_space(3))) unsigned int las_u32;

static __device__ __forceinline__ unsigned short f2bf(float f) {
  __hip_bfloat16 h = __float2bfloat16(f);
  return *reinterpret_cast<unsigned short*>(&h);
}
static __device__ __forceinline__ float bf2f(unsigned short u) {
  union { unsigned int u; float f; } c;
  c.u = ((unsigned int)u) << 16;
  return c.f;
}
static __device__ __forceinline__ float fast_tanh(float x) {
  float t = __expf(2.f * x);
  return (t - 1.f) / (t + 1.f);
}

// ---------------- embedding gather + convert to bf16 ----------------
__global__ void gather_emb(const int* __restrict__ x, const float* __restrict__ E,
                           unsigned short* __restrict__ A) {
  int m = blockIdx.x * 4 + (threadIdx.x >> 6);
  int lane = threadIdx.x & 63;
  int t = x[m];
  float4 v = reinterpret_cast<const float4*>(E + (size_t)t * NE)[lane];
  ushort4 o = make_ushort4(f2bf(v.x), f2bf(v.y), f2bf(v.z), f2bf(v.w));
  reinterpret_cast<ushort4*>(A + (size_t)m * NE)[lane] = o;
}

// ---------------- tiled transpose, f32 in -> (bf16|f32) out ----------------
template<typename T>
__global__ void transpose_conv(const float* __restrict__ in, T* __restrict__ out,
                               int R, int C) {
  __shared__ float tile[32][33];
  int c0 = blockIdx.x * 32, r0 = blockIdx.y * 32;
  int tx = threadIdx.x, ty = threadIdx.y;
  #pragma unroll
  for (int i = 0; i < 32; i += 8)
    tile[ty + i][tx] = in[(size_t)(r0 + ty + i) * C + (c0 + tx)];
  __syncthreads();
  #pragma unroll
  for (int i = 0; i < 32; i += 8) {
    float v = tile[tx][ty + i];
    if constexpr (sizeof(T) == 2)
      out[(size_t)(c0 + ty + i) * R + (r0 + tx)] = (T)f2bf(v);
    else
      out[(size_t)(c0 + ty + i) * R + (r0 + tx)] = (T)v;
  }
}

// ---------------- bf16 MFMA GEMM (xw = emb @ W + b0), XCD-swizzled --------
template<bool OUT_BF16>
__launch_bounds__(256)
__global__ void gemm_bt(const unsigned short* __restrict__ A,
                        const unsigned short* __restrict__ BT,
                        const float* __restrict__ bias,
                        void* __restrict__ out, int N, int K) {
  __shared__ unsigned short As[128 * 32];
  __shared__ unsigned short Bs[128 * 32];
  const int tid = threadIdx.x;
  const int lane = tid & 63, wave = tid >> 6;
  const int wr = wave >> 1, wc = wave & 1;
  int nwg = gridDim.x * gridDim.y;
  int bid0 = blockIdx.y * gridDim.x + blockIdx.x;
  int q = nwg >> 3, r8 = nwg & 7;
  int xcd = bid0 & 7, idx = bid0 >> 3;
  int bid = (xcd < r8 ? xcd * (q + 1) : r8 * (q + 1) + (xcd - r8) * q) + idx;
  const int m0 = (bid / gridDim.x) * 128, n0 = (bid % gridDim.x) * 128;
  const int lr = lane & 15, lg = lane >> 4;
  float4v acc[4][4] = {};

  for (int k0 = 0; k0 < K; k0 += 32) {
    #pragma unroll
    for (int qq = 0; qq < 2; ++qq) {
      int byteoff = qq * 4096 + tid * 16;
      int rr = byteoff >> 6, cb = byteoff & 63;
      const char* ga = (const char*)A + ((size_t)(m0 + rr) * K + k0) * 2 + cb;
      const char* gb = (const char*)BT + ((size_t)(n0 + rr) * K + k0) * 2 + cb;
      char* la = (char*)As + qq * 4096 + wave * 1024;
      char* lb = (char*)Bs + qq * 4096 + wave * 1024;
      __builtin_amdgcn_global_load_lds((gas_u32*)ga, (las_u32*)la, 16, 0, 0);
      __builtin_amdgcn_global_load_lds((gas_u32*)gb, (las_u32*)lb, 16, 0, 0);
    }
    __syncthreads();
    short8v a[4], b[4];
    #pragma unroll
    for (int i = 0; i < 4; ++i)
      a[i] = *(const short8v*)((const char*)As + (wr * 64 + i * 16 + lr) * 64 + lg * 16);
    #pragma unroll
    for (int j = 0; j < 4; ++j)
      b[j] = *(const short8v*)((const char*)Bs + (wc * 64 + j * 16 + lr) * 64 + lg * 16);
    #pragma unroll
    for (int i = 0; i < 4; ++i) {
      #pragma unroll
      for (int j = 0; j < 4; ++j)
        acc[i][j] = __builtin_amdgcn_mfma_f32_16x16x32_bf16(a[i], b[j], acc[i][j], 0, 0, 0);
    }
    __syncthreads();
  }
  #pragma unroll
  for (int i = 0; i < 4; ++i) {
    int row = m0 + wr * 64 + i * 16 + lg * 4;
    #pragma unroll
    for (int j = 0; j < 4; ++j) {
      int col = n0 + wc * 64 + j * 16 + lr;
      float bv = bias[col];
      #pragma unroll
      for (int rr = 0; rr < 4; ++rr) {
        float v = acc[i][j][rr] + bv;
        if constexpr (OUT_BF16)
          ((unsigned short*)out)[(size_t)(row + rr) * N + col] = f2bf(v);
        else
          ((float*)out)[(size_t)(row + rr) * N + col] = v;
      }
    }
  }
}

// ---------------- persistent GRU: 4-chain interleave, LLC exchange ----------
// 16 WGs x 256 thr. quad = blk>>3 owns groups 4q..4q+3 (8 batches); wq = blk&7
// owns dims [64wq, 64wq+64) of EVERY chain in the quad (U frags shared).
// Per super-step, 4 sequential phases (one per chain):
//   poll chain c (1 u64/thread, own slice skipped) -> h_lds[c][p] -> barrier
//   -> 48 MFMA -> in-wave D-transpose -> gates -> u64 publish + own LDS write.
// Each chain's publish->poll gap spans the other 3 phases -> LLC latency hidden.
// Exchange protocol per chain identical to R10 (agent atomics, data-as-flag).
#define SENT 0xFFFFFFFFu
__launch_bounds__(256, 1)
__global__ void gru_kernel(const unsigned short* __restrict__ xw,   // [4096][1536] bf16
                           const float* __restrict__ UT,            // [1536][512] f32
                           const float* __restrict__ bvec,          // b[2][1536] f32
                           unsigned int* __restrict__ Hex) {        // [257][8][512] u32, memset 0xFF
  const int blk = blockIdx.x, tid = threadIdx.x;
  const int quad = blk >> 3, wq = blk & 7;
  const int lane = tid & 63, w = tid >> 6;
  const int lg = lane >> 4, lr = lane & 15;
  __shared__ __align__(16) unsigned short h_lds[4][2][1024];  // 16KB
  __shared__ __align__(16) float scratch[4][96];

  const int D0w = 64 * wq + 16 * w;   // this wave's 16 dims (same in all chains)
  // ---- one-time: U cols -> VGPR B-fragments, 3 chains (z,r,h); shared ----
  short8v Bf[3][16];
  #pragma unroll
  for (int c = 0; c < 3; ++c) {
    const float* up = UT + (size_t)(c * 512 + D0w + lr) * 512 + lg * 8;
    #pragma unroll
    for (int kk = 0; kk < 16; ++kk) {
      float4 v0 = *(const float4*)(up + kk * 32);
      float4 v1 = *(const float4*)(up + kk * 32 + 4);
      short8v t;
      t[0] = (short)f2bf(v0.x); t[1] = (short)f2bf(v0.y);
      t[2] = (short)f2bf(v0.z); t[3] = (short)f2bf(v0.w);
      t[4] = (short)f2bf(v1.x); t[5] = (short)f2bf(v1.y);
      t[6] = (short)f2bf(v1.z); t[7] = (short)f2bf(v1.w);
      Bf[c][kk] = t;
    }
  }
  for (int i = tid; i < 1024; i += 256)
    reinterpret_cast<uint4*>(h_lds)[i] = make_uint4(0, 0, 0, 0);   // 16KB zero

  // ---- gate-lane constants (lane<32): b = lane&1, di = lane>>1 ----
  const int b = lane & 1, di = lane >> 1;
  const int d = D0w + di, hi = d & 1;
  float h_old[4] = {0.f, 0.f, 0.f, 0.f};
  float bz = 0.f, br = 0.f, bh = 0.f;
  const unsigned int* xp[4] = {nullptr, nullptr, nullptr, nullptr};
  if (lane < 32) {
    const float* brec = bvec + 1536;
    bz = brec[d]; br = brec[512 + d]; bh = brec[1024 + d];
    #pragma unroll
    for (int c = 0; c < 4; ++c)
      xp[c] = (const unsigned int*)xw +
              (size_t)((quad * 4 + c) * 2 + b) * 256 * 768 + (d >> 1);
  }
  // poll constants: thread t owns group-words 2t, 2t+1 (one u64)
  const bool own = ((tid >> 4) & 7) == wq;
  const int pbb = tid >> 7;
  const int pm  = (2 * tid) & 255;
  __syncthreads();

  int p = 0;
  for (int s = 0; s < 256; ++s) {
    #pragma unroll
    for (int c = 0; c < 4; ++c) {
      const int grp = quad * 4 + c;
      // xw prefetch for this chain/step (in flight during poll)
      unsigned int xzw = 0, xrw = 0, xhw = 0;
      if (lane < 32) {
        xzw = xp[c][0]; xrw = xp[c][256]; xhw = xp[c][512]; xp[c] += 768;
      }
      if (s > 0 && !own) {
        const unsigned long long* src =
            (const unsigned long long*)(Hex + (size_t)s * 4096 + grp * 512 + 2 * tid);
        unsigned long long v = __hip_atomic_load(src, __ATOMIC_RELAXED, __HIP_MEMORY_SCOPE_AGENT);
        while ((unsigned int)v == SENT || (unsigned int)(v >> 32) == SENT) {
          __builtin_amdgcn_s_sleep(1);
          v = __hip_atomic_load(src, __ATOMIC_RELAXED, __HIP_MEMORY_SCOPE_AGENT);
        }
        *(unsigned long long*)((char*)h_lds[c][p] + ((pbb * 1024 + pm * 4) ^ (pbb << 4))) = v;
      }
      __syncthreads();   // one barrier per phase

      // ---- rec: 3 independent MFMA chains on h_lds[c][p] ----
      float4v a0 = {}, a1 = {}, a2 = {};
      const char* hb = (const char*)h_lds[c][p];
      #pragma unroll
      for (int kk = 0; kk < 16; ++kk) {
        int off = ((lane & 1) * 1024 + kk * 64 + lg * 16) ^ ((lane & 1) << 4);
        short8v a = *(const short8v*)(hb + off);
        a0 = __builtin_amdgcn_mfma_f32_16x16x32_bf16(a, Bf[0][kk], a0, 0, 0, 0);
        a1 = __builtin_amdgcn_mfma_f32_16x16x32_bf16(a, Bf[1][kk], a1, 0, 0, 0);
        a2 = __builtin_amdgcn_mfma_f32_16x16x32_bf16(a, Bf[2][kk], a2, 0, 0, 0);
      }
      // in-wave D transpose: rows 0,1 (batches) live in lg==0 regs 0,1
      if (lg == 0) {
        *(float2*)&scratch[w][lr * 2]      = make_float2(a0[0], a0[1]);
        *(float2*)&scratch[w][32 + lr * 2] = make_float2(a1[0], a1[1]);
        *(float2*)&scratch[w][64 + lr * 2] = make_float2(a2[0], a2[1]);
      }
      // ---- gates: lanes 0..31, each owns (b, d) of chain c ----
      if (lane < 32) {
        float rz = scratch[w][di * 2 + b];
        float rr = scratch[w][32 + di * 2 + b];
        float rh = scratch[w][64 + di * 2 + b];
        float xz = bf2f((unsigned short)(hi ? (xzw >> 16) : (xzw & 0xffff)));
        float xr = bf2f((unsigned short)(hi ? (xrw >> 16) : (xrw & 0xffff)));
        float xh = bf2f((unsigned short)(hi ? (xhw >> 16) : (xhw & 0xffff)));
        float z = 1.f / (1.f + __expf(-(xz + rz + bz)));
        float r = 1.f / (1.f + __expf(-(xr + rr + br)));
        float hh = fast_tanh(xh + r * (rh + bh));
        h_old[c] = z * h_old[c] + (1.f - z) * hh;
        unsigned int mine = f2bf(h_old[c]);
        unsigned int pack = mine | ((unsigned int)__shfl_xor((int)mine, 2) << 16);
        unsigned int hip2 = (unsigned int)__shfl_xor((int)pack, 4);
        if ((lane & 6) == 0) {                   // lanes 0,1,8,9,16,17,24,25
          unsigned long long u = (unsigned long long)pack | ((unsigned long long)hip2 << 32);
          int m = 32 * wq + 8 * w + 2 * (lane >> 3);
          __hip_atomic_store((unsigned long long*)&Hex[(size_t)(s + 1) * 4096 + grp * 512 +
                                                       b * 256 + m],
                             u, __ATOMIC_RELAXED, __HIP_MEMORY_SCOPE_AGENT);
          *(unsigned long long*)((char*)h_lds[c][p ^ 1] + ((b * 1024 + m * 4) ^ (b << 4))) = u;
        }
      }
    }
    p ^= 1;
  }
}

// ---------------- decoder GEMM: out = h @ Wd^T + bd (A read from Hex) -------
__launch_bounds__(256)
__global__ void dec_gemm(const char* __restrict__ HexB,             // Hex bytes
                         const unsigned short* __restrict__ WdT,    // [32000][512] bf16
                         const float* __restrict__ bd,
                         float* __restrict__ out) {
  __shared__ unsigned short As[128 * 32];
  __shared__ unsigned short Bs[128 * 32];
  const int tid = threadIdx.x;
  const int lane = tid & 63, wave = tid >> 6;
  const int wr = wave >> 1, wc = wave & 1;
  const int lr = lane & 15, lg = lane >> 4;
  int bid0 = blockIdx.x;
  int bid = (bid0 & 7) * 1000 + (bid0 >> 3);        // 8000 = 8 XCD chunks x 1000
  const int mt = bid & 31, nt = bid >> 5;           // 32 m-tiles, 250 n-tiles
  const int b = mt >> 1, s0 = (mt & 1) * 128;
  const int n0 = nt * 128;
  float4v acc[4][4] = {};

  for (int k0 = 0; k0 < NH; k0 += 32) {
    #pragma unroll
    for (int qq = 0; qq < 2; ++qq) {
      int off = qq * 4096 + tid * 16;
      int rloc = off >> 6, cb = off & 63;
      int s = s0 + rloc;
      // h(s) for batch b lives at Hex[s+1][b>>1][b&1][0..255] (1KB row)
      const char* ga = HexB + ((size_t)(s + 1) * 4096 + (b >> 1) * 512 + (b & 1) * 256) * 4
                       + k0 * 2 + cb;
      const char* gb = (const char*)WdT + ((size_t)(n0 + rloc) * 512 + k0) * 2 + cb;
      __builtin_amdgcn_global_load_lds((gas_u32*)ga,
          (las_u32*)((char*)As + qq * 4096 + wave * 1024), 16, 0, 0);
      __builtin_amdgcn_global_load_lds((gas_u32*)gb,
          (las_u32*)((char*)Bs + qq * 4096 + wave * 1024), 16, 0, 0);
    }
    __syncthreads();
    short8v a[4], bb[4];
    #pragma unroll
    for (int i = 0; i < 4; ++i)
      a[i] = *(const short8v*)((const char*)As + (wr * 64 + i * 16 + lr) * 64 + lg * 16);
    #pragma unroll
    for (int j = 0; j < 4; ++j)
      bb[j] = *(const short8v*)((const char*)Bs + (wc * 64 + j * 16 + lr) * 64 + lg * 16);
    #pragma unroll
    for (int i = 0; i < 4; ++i) {
      #pragma unroll
      for (int j = 0; j < 4; ++j)
        acc[i][j] = __builtin_amdgcn_mfma_f32_16x16x32_bf16(a[i], bb[j], acc[i][j], 0, 0, 0);
    }
    __syncthreads();
  }
  #pragma unroll
  for (int i = 0; i < 4; ++i) {
    int l = wr * 64 + i * 16 + lg * 4;
    #pragma unroll
    for (int j = 0; j < 4; ++j) {
      int col = n0 + wc * 64 + j * 16 + lr;
      float bv = bd[col];
      #pragma unroll
      for (int rr = 0; rr < 4; ++rr) {
        size_t m = (size_t)(b * 256 + s0 + l + rr);
        __builtin_nontemporal_store(acc[i][j][rr] + bv, &out[m * NV + col]);
      }
    }
  }
}

// ---------------- launch ----------------
extern "C" void kernel_launch(void* const* d_in, const int* in_sizes, int n_in,
                              void* d_out, int out_size, void* d_ws, size_t ws_size,
                              hipStream_t stream) {
  const int*   x  = (const int*)d_in[0];
  const float* E  = (const float*)d_in[1];
  const float* W  = (const float*)d_in[2];
  const float* U  = (const float*)d_in[3];
  const float* bv = (const float*)d_in[4];
  const float* Wd = (const float*)d_in[5];
  const float* bd = (const float*)d_in[6];
  float* out = (float*)d_out;

  char* ws = (char*)d_ws;
  size_t off = 0;
  auto alloc = [&](size_t bytes) -> void* {
    void* p = ws + off;
    off = (off + bytes + 255) & ~(size_t)255;
    return p;
  };
  unsigned short* Aemb = (unsigned short*)alloc((size_t)NM * NE * 2);
  unsigned short* WT   = (unsigned short*)alloc((size_t)N3H * NE * 2);
  float*          UT   = (float*)alloc((size_t)N3H * NH * 4);
  unsigned short* xwb  = (unsigned short*)alloc((size_t)NM * N3H * 2);
  unsigned short* WdT  = (unsigned short*)alloc((size_t)NV * NH * 2);
  unsigned int*   Hex  = (unsigned int*)alloc((size_t)257 * 4096 * 4);

  hipMemsetAsync(Hex, 0xFF, (size_t)257 * 4096 * 4, stream);

  gather_emb<<<NM / 4, 256, 0, stream>>>(x, E, Aemb);
  transpose_conv<unsigned short><<<dim3(N3H / 32, NE / 32), dim3(32, 8), 0, stream>>>(W,  WT,  NE, N3H);
  transpose_conv<float>         <<<dim3(N3H / 32, NH / 32), dim3(32, 8), 0, stream>>>(U,  UT,  NH, N3H);
  transpose_conv<unsigned short><<<dim3(NV / 32,  NH / 32), dim3(32, 8), 0, stream>>>(Wd, WdT, NH, NV);

  gemm_bt<true><<<dim3(N3H / 128, NM / 128), 256, 0, stream>>>(Aemb, WT, bv, xwb, N3H, NE);

  gru_kernel<<<16, 256, 0, stream>>>(xwb, UT, bv, Hex);

  dec_gemm<<<8000, 256, 0, stream>>>((const char*)Hex, WdT, bd, out);
}

// Round 12
// 665.362 us; speedup vs baseline: 2.7941x; 2.7941x over previous
//
#include <hip/hip_runtime.h>
#include <hip/hip_bf16.h>
#include <stdint.h>
#include <stddef.h>

// ---------------- problem dims ----------------
#define NB 16
#define NS 256
#define NH 512
#define NE 256
#define NV 32000
#define NM (NB*NS)
#define N3H 1536

typedef __attribute__((ext_vector_type(8))) short short8v;
typedef __attribute__((ext_vector_type(4))) float float4v;
typedef __attribute__((address_space(1))) const unsigned int gas_u32;
typedef __attribute__((address_space(3))) unsigned int las_u32;

static __device__ __forceinline__ unsigned short f2bf(float f) {
  __hip_bfloat16 h = __float2bfloat16(f);
  return *reinterpret_cast<unsigned short*>(&h);
}
static __device__ __forceinline__ float bf2f(unsigned short u) {
  union { unsigned int u; float f; } c;
  c.u = ((unsigned int)u) << 16;
  return c.f;
}
static __device__ __forceinline__ float fast_tanh(float x) {
  float t = __expf(2.f * x);
  return (t - 1.f) / (t + 1.f);
}

// ---------------- embedding gather + convert to bf16 ----------------
__global__ void gather_emb(const int* __restrict__ x, const float* __restrict__ E,
                           unsigned short* __restrict__ A) {
  int m = blockIdx.x * 4 + (threadIdx.x >> 6);
  int lane = threadIdx.x & 63;
  int t = x[m];
  float4 v = reinterpret_cast<const float4*>(E + (size_t)t * NE)[lane];
  ushort4 o = make_ushort4(f2bf(v.x), f2bf(v.y), f2bf(v.z), f2bf(v.w));
  reinterpret_cast<ushort4*>(A + (size_t)m * NE)[lane] = o;
}

// ---------------- tiled transpose, f32 in -> (bf16|f32) out ----------------
template<typename T>
__global__ void transpose_conv(const float* __restrict__ in, T* __restrict__ out,
                               int R, int C) {
  __shared__ float tile[32][33];
  int c0 = blockIdx.x * 32, r0 = blockIdx.y * 32;
  int tx = threadIdx.x, ty = threadIdx.y;
  #pragma unroll
  for (int i = 0; i < 32; i += 8)
    tile[ty + i][tx] = in[(size_t)(r0 + ty + i) * C + (c0 + tx)];
  __syncthreads();
  #pragma unroll
  for (int i = 0; i < 32; i += 8) {
    float v = tile[tx][ty + i];
    if constexpr (sizeof(T) == 2)
      out[(size_t)(c0 + ty + i) * R + (r0 + tx)] = (T)f2bf(v);
    else
      out[(size_t)(c0 + ty + i) * R + (r0 + tx)] = (T)v;
  }
}

// ---------------- bf16 MFMA GEMM (xw = emb @ W + b0), XCD-swizzled --------
template<bool OUT_BF16>
__launch_bounds__(256)
__global__ void gemm_bt(const unsigned short* __restrict__ A,
                        const unsigned short* __restrict__ BT,
                        const float* __restrict__ bias,
                        void* __restrict__ out, int N, int K) {
  __shared__ unsigned short As[128 * 32];
  __shared__ unsigned short Bs[128 * 32];
  const int tid = threadIdx.x;
  const int lane = tid & 63, wave = tid >> 6;
  const int wr = wave >> 1, wc = wave & 1;
  int nwg = gridDim.x * gridDim.y;
  int bid0 = blockIdx.y * gridDim.x + blockIdx.x;
  int q = nwg >> 3, r8 = nwg & 7;
  int xcd = bid0 & 7, idx = bid0 >> 3;
  int bid = (xcd < r8 ? xcd * (q + 1) : r8 * (q + 1) + (xcd - r8) * q) + idx;
  const int m0 = (bid / gridDim.x) * 128, n0 = (bid % gridDim.x) * 128;
  const int lr = lane & 15, lg = lane >> 4;
  float4v acc[4][4] = {};

  for (int k0 = 0; k0 < K; k0 += 32) {
    #pragma unroll
    for (int qq = 0; qq < 2; ++qq) {
      int byteoff = qq * 4096 + tid * 16;
      int rr = byteoff >> 6, cb = byteoff & 63;
      const char* ga = (const char*)A + ((size_t)(m0 + rr) * K + k0) * 2 + cb;
      const char* gb = (const char*)BT + ((size_t)(n0 + rr) * K + k0) * 2 + cb;
      char* la = (char*)As + qq * 4096 + wave * 1024;
      char* lb = (char*)Bs + qq * 4096 + wave * 1024;
      __builtin_amdgcn_global_load_lds((gas_u32*)ga, (las_u32*)la, 16, 0, 0);
      __builtin_amdgcn_global_load_lds((gas_u32*)gb, (las_u32*)lb, 16, 0, 0);
    }
    __syncthreads();
    short8v a[4], b[4];
    #pragma unroll
    for (int i = 0; i < 4; ++i)
      a[i] = *(const short8v*)((const char*)As + (wr * 64 + i * 16 + lr) * 64 + lg * 16);
    #pragma unroll
    for (int j = 0; j < 4; ++j)
      b[j] = *(const short8v*)((const char*)Bs + (wc * 64 + j * 16 + lr) * 64 + lg * 16);
    #pragma unroll
    for (int i = 0; i < 4; ++i) {
      #pragma unroll
      for (int j = 0; j < 4; ++j)
        acc[i][j] = __builtin_amdgcn_mfma_f32_16x16x32_bf16(a[i], b[j], acc[i][j], 0, 0, 0);
    }
    __syncthreads();
  }
  #pragma unroll
  for (int i = 0; i < 4; ++i) {
    int row = m0 + wr * 64 + i * 16 + lg * 4;
    #pragma unroll
    for (int j = 0; j < 4; ++j) {
      int col = n0 + wc * 64 + j * 16 + lr;
      float bv = bias[col];
      #pragma unroll
      for (int rr = 0; rr < 4; ++rr) {
        float v = acc[i][j][rr] + bv;
        if constexpr (OUT_BF16)
          ((unsigned short*)out)[(size_t)(row + rr) * N + col] = f2bf(v);
        else
          ((float*)out)[(size_t)(row + rr) * N + col] = v;
      }
    }
  }
}

// ---------------- persistent GRU, LLC exchange (R10-proven, 427us) ----------
// 64 WGs x 256 thr. grp = blk>>3 owns batches {2grp, 2grp+1}; wq = blk&7 owns
// dims [64wq, 64wq+64). Wave w owns 16 dims; its 48 U-cols (z,r,h) live in
// VGPRs as 3 MFMA B-chains. All exchange via agent-scope atomics.
// Per step: poll 1 u64/thread (own slice skipped) -> h_lds[p] -> ONE barrier
// -> 48 MFMA -> in-wave D-transpose via scratch -> per-lane gates -> shfl
// aggregation -> u64 atomic stores to Hex[s+1] + own-slice LDS write.
#define SENT 0xFFFFFFFFu
__launch_bounds__(256, 1)
__global__ void gru_kernel(const unsigned short* __restrict__ xw,   // [4096][1536] bf16
                           const float* __restrict__ UT,            // [1536][512] f32
                           const float* __restrict__ bvec,          // b[2][1536] f32
                           unsigned int* __restrict__ Hex) {        // [257][8][512] u32, memset 0xFF
  const int blk = blockIdx.x, tid = threadIdx.x;
  const int grp = blk >> 3, wq = blk & 7;
  const int lane = tid & 63, w = tid >> 6;
  const int lg = lane >> 4, lr = lane & 15;
  __shared__ __align__(16) unsigned short h_lds[2][1024];  // [parity][2 batches x 512]
  __shared__ __align__(16) float scratch[4][96];           // per-wave D transpose

  const int D0w = 64 * wq + 16 * w;   // this wave's 16 dims
  // ---- one-time: U cols -> VGPR B-fragments, 3 chains (z,r,h) ----
  short8v Bf[3][16];
  #pragma unroll
  for (int c = 0; c < 3; ++c) {
    const float* up = UT + (size_t)(c * 512 + D0w + lr) * 512 + lg * 8;
    #pragma unroll
    for (int kk = 0; kk < 16; ++kk) {
      float4 v0 = *(const float4*)(up + kk * 32);
      float4 v1 = *(const float4*)(up + kk * 32 + 4);
      short8v t;
      t[0] = (short)f2bf(v0.x); t[1] = (short)f2bf(v0.y);
      t[2] = (short)f2bf(v0.z); t[3] = (short)f2bf(v0.w);
      t[4] = (short)f2bf(v1.x); t[5] = (short)f2bf(v1.y);
      t[6] = (short)f2bf(v1.z); t[7] = (short)f2bf(v1.w);
      Bf[c][kk] = t;
    }
  }
  reinterpret_cast<uint4*>(h_lds)[tid] = make_uint4(0, 0, 0, 0);  // 256*16B = 4KB

  // ---- gate-lane constants (lane<32): b = lane&1, di = lane>>1 ----
  const int b = lane & 1, di = lane >> 1;
  const int d = D0w + di, hi = d & 1;
  float h_old = 0.f, bz = 0.f, br = 0.f, bh = 0.f;
  const unsigned int* xp = nullptr;
  if (lane < 32) {
    const float* brec = bvec + 1536;
    bz = brec[d]; br = brec[512 + d]; bh = brec[1024 + d];
    xp = (const unsigned int*)xw + (size_t)(grp * 2 + b) * 256 * 768 + (d >> 1);
  }
  // poll constants: thread t owns group-words 2t, 2t+1 (one u64)
  const bool own = ((tid >> 4) & 7) == wq;       // words within own 64-dim slice
  const int pbb = tid >> 7;                      // batch of polled words
  const int pm  = (2 * tid) & 255;               // within-batch word (even)
  __syncthreads();

  int p = 0;
  for (int s = 0; s < 256; ++s) {
    // xw prefetch for this step (in flight during poll)
    unsigned int xzw = 0, xrw = 0, xhw = 0;
    if (lane < 32) { xzw = xp[0]; xrw = xp[256]; xhw = xp[512]; xp += 768; }

    if (s > 0 && !own) {
      const unsigned long long* src =
          (const unsigned long long*)(Hex + (size_t)s * 4096 + grp * 512 + 2 * tid);
      unsigned long long v = __hip_atomic_load(src, __ATOMIC_RELAXED, __HIP_MEMORY_SCOPE_AGENT);
      while ((unsigned int)v == SENT || (unsigned int)(v >> 32) == SENT) {
        __builtin_amdgcn_s_sleep(1);
        v = __hip_atomic_load(src, __ATOMIC_RELAXED, __HIP_MEMORY_SCOPE_AGENT);
      }
      *(unsigned long long*)((char*)h_lds[p] + ((pbb * 1024 + pm * 4) ^ (pbb << 4))) = v;
    }
    __syncthreads();   // the only barrier per step

    // ---- rec: 3 independent MFMA chains on h_lds[p] ----
    float4v a0 = {}, a1 = {}, a2 = {};
    const char* hb = (const char*)h_lds[p];
    #pragma unroll
    for (int kk = 0; kk < 16; ++kk) {
      int off = ((lane & 1) * 1024 + kk * 64 + lg * 16) ^ ((lane & 1) << 4);
      short8v a = *(const short8v*)(hb + off);
      a0 = __builtin_amdgcn_mfma_f32_16x16x32_bf16(a, Bf[0][kk], a0, 0, 0, 0);
      a1 = __builtin_amdgcn_mfma_f32_16x16x32_bf16(a, Bf[1][kk], a1, 0, 0, 0);
      a2 = __builtin_amdgcn_mfma_f32_16x16x32_bf16(a, Bf[2][kk], a2, 0, 0, 0);
    }
    // in-wave D transpose: rows 0,1 (batches) live in lg==0 regs 0,1
    if (lg == 0) {
      *(float2*)&scratch[w][lr * 2]      = make_float2(a0[0], a0[1]);
      *(float2*)&scratch[w][32 + lr * 2] = make_float2(a1[0], a1[1]);
      *(float2*)&scratch[w][64 + lr * 2] = make_float2(a2[0], a2[1]);
    }
    // ---- gates: lanes 0..31, each owns (b, d) ----
    if (lane < 32) {
      float rz = scratch[w][di * 2 + b];
      float rr = scratch[w][32 + di * 2 + b];
      float rh = scratch[w][64 + di * 2 + b];
      float xz = bf2f((unsigned short)(hi ? (xzw >> 16) : (xzw & 0xffff)));
      float xr = bf2f((unsigned short)(hi ? (xrw >> 16) : (xrw & 0xffff)));
      float xh = bf2f((unsigned short)(hi ? (xhw >> 16) : (xhw & 0xffff)));
      float z = 1.f / (1.f + __expf(-(xz + rz + bz)));
      float r = 1.f / (1.f + __expf(-(xr + rr + br)));
      float hh = fast_tanh(xh + r * (rh + bh));
      h_old = z * h_old + (1.f - z) * hh;
      unsigned int mine = f2bf(h_old);
      // dword pack (dims d, d+1) on lanes with even di
      unsigned int pack = mine | ((unsigned int)__shfl_xor((int)mine, 2) << 16);
      // u64 pack (words m, m+1) from partner lane+4
      unsigned int hip2 = (unsigned int)__shfl_xor((int)pack, 4);
      if ((lane & 6) == 0) {                     // lanes 0,1,8,9,16,17,24,25
        unsigned long long u = (unsigned long long)pack | ((unsigned long long)hip2 << 32);
        int m = 32 * wq + 8 * w + 2 * (lane >> 3);          // within-batch word
        __hip_atomic_store((unsigned long long*)&Hex[(size_t)(s + 1) * 4096 + grp * 512 +
                                                     b * 256 + m],
                           u, __ATOMIC_RELAXED, __HIP_MEMORY_SCOPE_AGENT);
        *(unsigned long long*)((char*)h_lds[p ^ 1] + ((b * 1024 + m * 4) ^ (b << 4))) = u;
      }
    }
    p ^= 1;
  }
}

// ---------------- decoder GEMM: out = h @ Wd^T + bd (A read from Hex) -------
// 8000 blocks x 256 thr (~4 WGs/CU). BK=64: two proven 32-k sub-tiles staged
// per barrier pair -> 8 k-iters, 64 MFMA between barriers (vs 32). bid n-major
// within 8 XCD chunks so WdT panels stay XCD-L2-resident. NT f32 stores.
__launch_bounds__(256)
__global__ void dec_gemm(const char* __restrict__ HexB,             // Hex bytes
                         const unsigned short* __restrict__ WdT,    // [32000][512] bf16
                         const float* __restrict__ bd,
                         float* __restrict__ out) {
  __shared__ unsigned short As[2][128 * 32];   // [half][row][32k]
  __shared__ unsigned short Bs[2][128 * 32];
  const int tid = threadIdx.x;
  const int lane = tid & 63, wave = tid >> 6;
  const int wr = wave >> 1, wc = wave & 1;
  const int lr = lane & 15, lg = lane >> 4;
  int bid0 = blockIdx.x;
  int bid = (bid0 & 7) * 1000 + (bid0 >> 3);        // 8000 = 8 XCD chunks x 1000
  const int mt = bid & 31, nt = bid >> 5;           // 32 m-tiles, 250 n-tiles
  const int b = mt >> 1, s0 = (mt & 1) * 128;
  const int n0 = nt * 128;
  const size_t hex_row_base = ((size_t)(b >> 1) * 512 + (b & 1) * 256) * 4;
  float4v acc[4][4] = {};

  for (int k0 = 0; k0 < NH; k0 += 64) {
    #pragma unroll
    for (int qq = 0; qq < 4; ++qq) {
      int half = qq >> 1, q2 = qq & 1;
      int off = q2 * 4096 + tid * 16;
      int rloc = off >> 6, cb = off & 63;
      int s = s0 + rloc;
      const char* ga = HexB + (size_t)(s + 1) * 16384 + hex_row_base
                       + (k0 + half * 32) * 2 + cb;
      const char* gb = (const char*)WdT + ((size_t)(n0 + rloc) * 512 + k0 + half * 32) * 2 + cb;
      __builtin_amdgcn_global_load_lds((gas_u32*)ga,
          (las_u32*)((char*)As[half] + q2 * 4096 + wave * 1024), 16, 0, 0);
      __builtin_amdgcn_global_load_lds((gas_u32*)gb,
          (las_u32*)((char*)Bs[half] + q2 * 4096 + wave * 1024), 16, 0, 0);
    }
    __syncthreads();
    #pragma unroll
    for (int h = 0; h < 2; ++h) {
      short8v a[4], bb[4];
      #pragma unroll
      for (int i = 0; i < 4; ++i)
        a[i] = *(const short8v*)((const char*)As[h] + (wr * 64 + i * 16 + lr) * 64 + lg * 16);
      #pragma unroll
      for (int j = 0; j < 4; ++j)
        bb[j] = *(const short8v*)((const char*)Bs[h] + (wc * 64 + j * 16 + lr) * 64 + lg * 16);
      #pragma unroll
      for (int i = 0; i < 4; ++i) {
        #pragma unroll
        for (int j = 0; j < 4; ++j)
          acc[i][j] = __builtin_amdgcn_mfma_f32_16x16x32_bf16(a[i], bb[j], acc[i][j], 0, 0, 0);
      }
    }
    __syncthreads();
  }
  #pragma unroll
  for (int i = 0; i < 4; ++i) {
    int l = wr * 64 + i * 16 + lg * 4;
    #pragma unroll
    for (int j = 0; j < 4; ++j) {
      int col = n0 + wc * 64 + j * 16 + lr;
      float bv = bd[col];
      #pragma unroll
      for (int rr = 0; rr < 4; ++rr) {
        size_t m = (size_t)(b * 256 + s0 + l + rr);
        __builtin_nontemporal_store(acc[i][j][rr] + bv, &out[m * NV + col]);
      }
    }
  }
}

// ---------------- launch ----------------
extern "C" void kernel_launch(void* const* d_in, const int* in_sizes, int n_in,
                              void* d_out, int out_size, void* d_ws, size_t ws_size,
                              hipStream_t stream) {
  const int*   x  = (const int*)d_in[0];
  const float* E  = (const float*)d_in[1];
  const float* W  = (const float*)d_in[2];
  const float* U  = (const float*)d_in[3];
  const float* bv = (const float*)d_in[4];
  const float* Wd = (const float*)d_in[5];
  const float* bd = (const float*)d_in[6];
  float* out = (float*)d_out;

  char* ws = (char*)d_ws;
  size_t off = 0;
  auto alloc = [&](size_t bytes) -> void* {
    void* p = ws + off;
    off = (off + bytes + 255) & ~(size_t)255;
    return p;
  };
  unsigned short* Aemb = (unsigned short*)alloc((size_t)NM * NE * 2);
  unsigned short* WT   = (unsigned short*)alloc((size_t)N3H * NE * 2);
  float*          UT   = (float*)alloc((size_t)N3H * NH * 4);
  unsigned short* xwb  = (unsigned short*)alloc((size_t)NM * N3H * 2);
  unsigned short* WdT  = (unsigned short*)alloc((size_t)NV * NH * 2);
  unsigned int*   Hex  = (unsigned int*)alloc((size_t)257 * 4096 * 4);

  hipMemsetAsync(Hex, 0xFF, (size_t)257 * 4096 * 4, stream);

  gather_emb<<<NM / 4, 256, 0, stream>>>(x, E, Aemb);
  transpose_conv<unsigned short><<<dim3(N3H / 32, NE / 32), dim3(32, 8), 0, stream>>>(W,  WT,  NE, N3H);
  transpose_conv<float>         <<<dim3(N3H / 32, NH / 32), dim3(32, 8), 0, stream>>>(U,  UT,  NH, N3H);
  transpose_conv<unsigned short><<<dim3(NV / 32,  NH / 32), dim3(32, 8), 0, stream>>>(Wd, WdT, NH, NV);

  gemm_bt<true><<<dim3(N3H / 128, NM / 128), 256, 0, stream>>>(Aemb, WT, bv, xwb, N3H, NE);

  gru_kernel<<<64, 256, 0, stream>>>(xwb, UT, bv, Hex);

  dec_gemm<<<8000, 256, 0, stream>>>((const char*)Hex, WdT, bd, out);
}

// Round 13
// 661.237 us; speedup vs baseline: 2.8115x; 1.0062x over previous
//
#include <hip/hip_runtime.h>
#include <hip/hip_bf16.h>
#include <stdint.h>
#include <stddef.h>

// ---------------- problem dims ----------------
#define NB 16
#define NS 256
#define NH 512
#define NE 256
#define NV 32000
#define NM (NB*NS)
#define N3H 1536

typedef __attribute__((ext_vector_type(8))) short short8v;
typedef __attribute__((ext_vector_type(4))) float float4v;
typedef __attribute__((address_space(1))) const unsigned int gas_u32;
typedef __attribute__((address_space(3))) unsigned int las_u32;

static __device__ __forceinline__ unsigned short f2bf(float f) {
  __hip_bfloat16 h = __float2bfloat16(f);
  return *reinterpret_cast<unsigned short*>(&h);
}
static __device__ __forceinline__ float bf2f(unsigned short u) {
  union { unsigned int u; float f; } c;
  c.u = ((unsigned int)u) << 16;
  return c.f;
}
static __device__ __forceinline__ float fast_tanh(float x) {
  float t = __expf(2.f * x);
  return (t - 1.f) / (t + 1.f);
}

// ---------------- merged prep: gather + W/U/Wd transposes -------------------
// One launch, roles by blockIdx range (all independent):
//   [0,1024):            gather 4 rows/block of E[x] -> Aemb bf16
//   [1024,1408):         W  (256x1536 f32)  -> WT  (1536x256 bf16)
//   [1408,2176):         U  (512x1536 f32)  -> UT  (1536x512 f32)
//   [2176,18176):        Wd (512x32000 f32) -> WdT (32000x512 bf16)
__launch_bounds__(256)
__global__ void prep_kernel(const int* __restrict__ x, const float* __restrict__ E,
                            const float* __restrict__ W, const float* __restrict__ U,
                            const float* __restrict__ Wd,
                            unsigned short* __restrict__ Aemb,
                            unsigned short* __restrict__ WT,
                            float* __restrict__ UT,
                            unsigned short* __restrict__ WdT) {
  const int blk = blockIdx.x, tid = threadIdx.x;
  if (blk < 1024) {
    // ---- gather ----
    int m = blk * 4 + (tid >> 6);
    int lane = tid & 63;
    int t = x[m];
    float4 v = reinterpret_cast<const float4*>(E + (size_t)t * NE)[lane];
    ushort4 o = make_ushort4(f2bf(v.x), f2bf(v.y), f2bf(v.z), f2bf(v.w));
    reinterpret_cast<ushort4*>(Aemb + (size_t)m * NE)[lane] = o;
    return;
  }
  // ---- transpose roles: 32x32 tile, block = 256 thr (tx 0..31, ty 0..7) ----
  __shared__ float tile[32][33];
  const float* in; int R, C, c0, r0; bool bf16out;
  unsigned short* outb = nullptr; float* outf = nullptr;
  if (blk < 1408) {
    int idx = blk - 1024;                 // 48 x 8
    in = W;  R = NE;  C = N3H; c0 = (idx % 48) * 32; r0 = (idx / 48) * 32;
    bf16out = true;  outb = WT;
  } else if (blk < 2176) {
    int idx = blk - 1408;                 // 48 x 16
    in = U;  R = NH;  C = N3H; c0 = (idx % 48) * 32; r0 = (idx / 48) * 32;
    bf16out = false; outf = UT;
  } else {
    int idx = blk - 2176;                 // 1000 x 16
    in = Wd; R = NH;  C = NV;  c0 = (idx % 1000) * 32; r0 = (idx / 1000) * 32;
    bf16out = true;  outb = WdT;
  }
  const int tx = tid & 31, ty = tid >> 5;
  #pragma unroll
  for (int i = 0; i < 32; i += 8)
    tile[ty + i][tx] = in[(size_t)(r0 + ty + i) * C + (c0 + tx)];
  __syncthreads();
  #pragma unroll
  for (int i = 0; i < 32; i += 8) {
    float v = tile[tx][ty + i];
    if (bf16out)
      outb[(size_t)(c0 + ty + i) * R + (r0 + tx)] = f2bf(v);
    else
      outf[(size_t)(c0 + ty + i) * R + (r0 + tx)] = v;
  }
}

// ---------------- bf16 MFMA GEMM (xw = emb @ W + b0), XCD-swizzled --------
template<bool OUT_BF16>
__launch_bounds__(256)
__global__ void gemm_bt(const unsigned short* __restrict__ A,
                        const unsigned short* __restrict__ BT,
                        const float* __restrict__ bias,
                        void* __restrict__ out, int N, int K) {
  __shared__ unsigned short As[128 * 32];
  __shared__ unsigned short Bs[128 * 32];
  const int tid = threadIdx.x;
  const int lane = tid & 63, wave = tid >> 6;
  const int wr = wave >> 1, wc = wave & 1;
  int nwg = gridDim.x * gridDim.y;
  int bid0 = blockIdx.y * gridDim.x + blockIdx.x;
  int q = nwg >> 3, r8 = nwg & 7;
  int xcd = bid0 & 7, idx = bid0 >> 3;
  int bid = (xcd < r8 ? xcd * (q + 1) : r8 * (q + 1) + (xcd - r8) * q) + idx;
  const int m0 = (bid / gridDim.x) * 128, n0 = (bid % gridDim.x) * 128;
  const int lr = lane & 15, lg = lane >> 4;
  float4v acc[4][4] = {};

  for (int k0 = 0; k0 < K; k0 += 32) {
    #pragma unroll
    for (int qq = 0; qq < 2; ++qq) {
      int byteoff = qq * 4096 + tid * 16;
      int rr = byteoff >> 6, cb = byteoff & 63;
      const char* ga = (const char*)A + ((size_t)(m0 + rr) * K + k0) * 2 + cb;
      const char* gb = (const char*)BT + ((size_t)(n0 + rr) * K + k0) * 2 + cb;
      char* la = (char*)As + qq * 4096 + wave * 1024;
      char* lb = (char*)Bs + qq * 4096 + wave * 1024;
      __builtin_amdgcn_global_load_lds((gas_u32*)ga, (las_u32*)la, 16, 0, 0);
      __builtin_amdgcn_global_load_lds((gas_u32*)gb, (las_u32*)lb, 16, 0, 0);
    }
    __syncthreads();
    short8v a[4], b[4];
    #pragma unroll
    for (int i = 0; i < 4; ++i)
      a[i] = *(const short8v*)((const char*)As + (wr * 64 + i * 16 + lr) * 64 + lg * 16);
    #pragma unroll
    for (int j = 0; j < 4; ++j)
      b[j] = *(const short8v*)((const char*)Bs + (wc * 64 + j * 16 + lr) * 64 + lg * 16);
    #pragma unroll
    for (int i = 0; i < 4; ++i) {
      #pragma unroll
      for (int j = 0; j < 4; ++j)
        acc[i][j] = __builtin_amdgcn_mfma_f32_16x16x32_bf16(a[i], b[j], acc[i][j], 0, 0, 0);
    }
    __syncthreads();
  }
  #pragma unroll
  for (int i = 0; i < 4; ++i) {
    int row = m0 + wr * 64 + i * 16 + lg * 4;
    #pragma unroll
    for (int j = 0; j < 4; ++j) {
      int col = n0 + wc * 64 + j * 16 + lr;
      float bv = bias[col];
      #pragma unroll
      for (int rr = 0; rr < 4; ++rr) {
        float v = acc[i][j][rr] + bv;
        if constexpr (OUT_BF16)
          ((unsigned short*)out)[(size_t)(row + rr) * N + col] = f2bf(v);
        else
          ((float*)out)[(size_t)(row + rr) * N + col] = v;
      }
    }
  }
}

// ---------------- persistent GRU, LLC exchange (R10-proven, 427us) ----------
// 64 WGs x 256 thr. grp = blk>>3 owns batches {2grp, 2grp+1}; wq = blk&7 owns
// dims [64wq, 64wq+64). Wave w owns 16 dims; its 48 U-cols (z,r,h) live in
// VGPRs as 3 MFMA B-chains. All exchange via agent-scope atomics.
// Per step: poll 1 u64/thread (own slice skipped) -> h_lds[p] -> ONE barrier
// -> 48 MFMA -> in-wave D-transpose via scratch -> per-lane gates -> shfl
// aggregation -> u64 atomic stores to Hex[s+1] + own-slice LDS write.
#define SENT 0xFFFFFFFFu
__launch_bounds__(256, 1)
__global__ void gru_kernel(const unsigned short* __restrict__ xw,   // [4096][1536] bf16
                           const float* __restrict__ UT,            // [1536][512] f32
                           const float* __restrict__ bvec,          // b[2][1536] f32
                           unsigned int* __restrict__ Hex) {        // [257][8][512] u32, memset 0xFF
  const int blk = blockIdx.x, tid = threadIdx.x;
  const int grp = blk >> 3, wq = blk & 7;
  const int lane = tid & 63, w = tid >> 6;
  const int lg = lane >> 4, lr = lane & 15;
  __shared__ __align__(16) unsigned short h_lds[2][1024];  // [parity][2 batches x 512]
  __shared__ __align__(16) float scratch[4][96];           // per-wave D transpose

  const int D0w = 64 * wq + 16 * w;   // this wave's 16 dims
  // ---- one-time: U cols -> VGPR B-fragments, 3 chains (z,r,h) ----
  short8v Bf[3][16];
  #pragma unroll
  for (int c = 0; c < 3; ++c) {
    const float* up = UT + (size_t)(c * 512 + D0w + lr) * 512 + lg * 8;
    #pragma unroll
    for (int kk = 0; kk < 16; ++kk) {
      float4 v0 = *(const float4*)(up + kk * 32);
      float4 v1 = *(const float4*)(up + kk * 32 + 4);
      short8v t;
      t[0] = (short)f2bf(v0.x); t[1] = (short)f2bf(v0.y);
      t[2] = (short)f2bf(v0.z); t[3] = (short)f2bf(v0.w);
      t[4] = (short)f2bf(v1.x); t[5] = (short)f2bf(v1.y);
      t[6] = (short)f2bf(v1.z); t[7] = (short)f2bf(v1.w);
      Bf[c][kk] = t;
    }
  }
  reinterpret_cast<uint4*>(h_lds)[tid] = make_uint4(0, 0, 0, 0);  // 256*16B = 4KB

  // ---- gate-lane constants (lane<32): b = lane&1, di = lane>>1 ----
  const int b = lane & 1, di = lane >> 1;
  const int d = D0w + di, hi = d & 1;
  float h_old = 0.f, bz = 0.f, br = 0.f, bh = 0.f;
  const unsigned int* xp = nullptr;
  if (lane < 32) {
    const float* brec = bvec + 1536;
    bz = brec[d]; br = brec[512 + d]; bh = brec[1024 + d];
    xp = (const unsigned int*)xw + (size_t)(grp * 2 + b) * 256 * 768 + (d >> 1);
  }
  // poll constants: thread t owns group-words 2t, 2t+1 (one u64)
  const bool own = ((tid >> 4) & 7) == wq;       // words within own 64-dim slice
  const int pbb = tid >> 7;                      // batch of polled words
  const int pm  = (2 * tid) & 255;               // within-batch word (even)
  __syncthreads();

  int p = 0;
  for (int s = 0; s < 256; ++s) {
    // xw prefetch for this step (in flight during poll)
    unsigned int xzw = 0, xrw = 0, xhw = 0;
    if (lane < 32) { xzw = xp[0]; xrw = xp[256]; xhw = xp[512]; xp += 768; }

    if (s > 0 && !own) {
      const unsigned long long* src =
          (const unsigned long long*)(Hex + (size_t)s * 4096 + grp * 512 + 2 * tid);
      unsigned long long v = __hip_atomic_load(src, __ATOMIC_RELAXED, __HIP_MEMORY_SCOPE_AGENT);
      while ((unsigned int)v == SENT || (unsigned int)(v >> 32) == SENT) {
        __builtin_amdgcn_s_sleep(1);
        v = __hip_atomic_load(src, __ATOMIC_RELAXED, __HIP_MEMORY_SCOPE_AGENT);
      }
      *(unsigned long long*)((char*)h_lds[p] + ((pbb * 1024 + pm * 4) ^ (pbb << 4))) = v;
    }
    __syncthreads();   // the only barrier per step

    // ---- rec: 3 independent MFMA chains on h_lds[p] ----
    float4v a0 = {}, a1 = {}, a2 = {};
    const char* hb = (const char*)h_lds[p];
    #pragma unroll
    for (int kk = 0; kk < 16; ++kk) {
      int off = ((lane & 1) * 1024 + kk * 64 + lg * 16) ^ ((lane & 1) << 4);
      short8v a = *(const short8v*)(hb + off);
      a0 = __builtin_amdgcn_mfma_f32_16x16x32_bf16(a, Bf[0][kk], a0, 0, 0, 0);
      a1 = __builtin_amdgcn_mfma_f32_16x16x32_bf16(a, Bf[1][kk], a1, 0, 0, 0);
      a2 = __builtin_amdgcn_mfma_f32_16x16x32_bf16(a, Bf[2][kk], a2, 0, 0, 0);
    }
    // in-wave D transpose: rows 0,1 (batches) live in lg==0 regs 0,1
    if (lg == 0) {
      *(float2*)&scratch[w][lr * 2]      = make_float2(a0[0], a0[1]);
      *(float2*)&scratch[w][32 + lr * 2] = make_float2(a1[0], a1[1]);
      *(float2*)&scratch[w][64 + lr * 2] = make_float2(a2[0], a2[1]);
    }
    // ---- gates: lanes 0..31, each owns (b, d) ----
    if (lane < 32) {
      float rz = scratch[w][di * 2 + b];
      float rr = scratch[w][32 + di * 2 + b];
      float rh = scratch[w][64 + di * 2 + b];
      float xz = bf2f((unsigned short)(hi ? (xzw >> 16) : (xzw & 0xffff)));
      float xr = bf2f((unsigned short)(hi ? (xrw >> 16) : (xrw & 0xffff)));
      float xh = bf2f((unsigned short)(hi ? (xhw >> 16) : (xhw & 0xffff)));
      float z = 1.f / (1.f + __expf(-(xz + rz + bz)));
      float r = 1.f / (1.f + __expf(-(xr + rr + br)));
      float hh = fast_tanh(xh + r * (rh + bh));
      h_old = z * h_old + (1.f - z) * hh;
      unsigned int mine = f2bf(h_old);
      // dword pack (dims d, d+1) on lanes with even di
      unsigned int pack = mine | ((unsigned int)__shfl_xor((int)mine, 2) << 16);
      // u64 pack (words m, m+1) from partner lane+4
      unsigned int hip2 = (unsigned int)__shfl_xor((int)pack, 4);
      if ((lane & 6) == 0) {                     // lanes 0,1,8,9,16,17,24,25
        unsigned long long u = (unsigned long long)pack | ((unsigned long long)hip2 << 32);
        int m = 32 * wq + 8 * w + 2 * (lane >> 3);          // within-batch word
        __hip_atomic_store((unsigned long long*)&Hex[(size_t)(s + 1) * 4096 + grp * 512 +
                                                     b * 256 + m],
                           u, __ATOMIC_RELAXED, __HIP_MEMORY_SCOPE_AGENT);
        *(unsigned long long*)((char*)h_lds[p ^ 1] + ((b * 1024 + m * 4) ^ (b << 4))) = u;
      }
    }
    p ^= 1;
  }
}

// ---------------- decoder GEMM: out = h @ Wd^T + bd (A read from Hex) -------
// 8000 blocks x 256 thr (~4 WGs/CU). BK=64: two 32-k sub-tiles staged per
// barrier pair -> 8 k-iters, 64 MFMA between barriers. bid n-major within
// 8 XCD chunks so WdT panels stay XCD-L2-resident. NT f32 stores.
__launch_bounds__(256)
__global__ void dec_gemm(const char* __restrict__ HexB,             // Hex bytes
                         const unsigned short* __restrict__ WdT,    // [32000][512] bf16
                         const float* __restrict__ bd,
                         float* __restrict__ out) {
  __shared__ unsigned short As[2][128 * 32];   // [half][row][32k]
  __shared__ unsigned short Bs[2][128 * 32];
  const int tid = threadIdx.x;
  const int lane = tid & 63, wave = tid >> 6;
  const int wr = wave >> 1, wc = wave & 1;
  const int lr = lane & 15, lg = lane >> 4;
  int bid0 = blockIdx.x;
  int bid = (bid0 & 7) * 1000 + (bid0 >> 3);        // 8000 = 8 XCD chunks x 1000
  const int mt = bid & 31, nt = bid >> 5;           // 32 m-tiles, 250 n-tiles
  const int b = mt >> 1, s0 = (mt & 1) * 128;
  const int n0 = nt * 128;
  const size_t hex_row_base = ((size_t)(b >> 1) * 512 + (b & 1) * 256) * 4;
  float4v acc[4][4] = {};

  for (int k0 = 0; k0 < NH; k0 += 64) {
    #pragma unroll
    for (int qq = 0; qq < 4; ++qq) {
      int half = qq >> 1, q2 = qq & 1;
      int off = q2 * 4096 + tid * 16;
      int rloc = off >> 6, cb = off & 63;
      int s = s0 + rloc;
      const char* ga = HexB + (size_t)(s + 1) * 16384 + hex_row_base
                       + (k0 + half * 32) * 2 + cb;
      const char* gb = (const char*)WdT + ((size_t)(n0 + rloc) * 512 + k0 + half * 32) * 2 + cb;
      __builtin_amdgcn_global_load_lds((gas_u32*)ga,
          (las_u32*)((char*)As[half] + q2 * 4096 + wave * 1024), 16, 0, 0);
      __builtin_amdgcn_global_load_lds((gas_u32*)gb,
          (las_u32*)((char*)Bs[half] + q2 * 4096 + wave * 1024), 16, 0, 0);
    }
    __syncthreads();
    #pragma unroll
    for (int h = 0; h < 2; ++h) {
      short8v a[4], bb[4];
      #pragma unroll
      for (int i = 0; i < 4; ++i)
        a[i] = *(const short8v*)((const char*)As[h] + (wr * 64 + i * 16 + lr) * 64 + lg * 16);
      #pragma unroll
      for (int j = 0; j < 4; ++j)
        bb[j] = *(const short8v*)((const char*)Bs[h] + (wc * 64 + j * 16 + lr) * 64 + lg * 16);
      #pragma unroll
      for (int i = 0; i < 4; ++i) {
        #pragma unroll
        for (int j = 0; j < 4; ++j)
          acc[i][j] = __builtin_amdgcn_mfma_f32_16x16x32_bf16(a[i], bb[j], acc[i][j], 0, 0, 0);
      }
    }
    __syncthreads();
  }
  #pragma unroll
  for (int i = 0; i < 4; ++i) {
    int l = wr * 64 + i * 16 + lg * 4;
    #pragma unroll
    for (int j = 0; j < 4; ++j) {
      int col = n0 + wc * 64 + j * 16 + lr;
      float bv = bd[col];
      #pragma unroll
      for (int rr = 0; rr < 4; ++rr) {
        size_t m = (size_t)(b * 256 + s0 + l + rr);
        __builtin_nontemporal_store(acc[i][j][rr] + bv, &out[m * NV + col]);
      }
    }
  }
}

// ---------------- launch ----------------
extern "C" void kernel_launch(void* const* d_in, const int* in_sizes, int n_in,
                              void* d_out, int out_size, void* d_ws, size_t ws_size,
                              hipStream_t stream) {
  const int*   x  = (const int*)d_in[0];
  const float* E  = (const float*)d_in[1];
  const float* W  = (const float*)d_in[2];
  const float* U  = (const float*)d_in[3];
  const float* bv = (const float*)d_in[4];
  const float* Wd = (const float*)d_in[5];
  const float* bd = (const float*)d_in[6];
  float* out = (float*)d_out;

  char* ws = (char*)d_ws;
  size_t off = 0;
  auto alloc = [&](size_t bytes) -> void* {
    void* p = ws + off;
    off = (off + bytes + 255) & ~(size_t)255;
    return p;
  };
  unsigned short* Aemb = (unsigned short*)alloc((size_t)NM * NE * 2);
  unsigned short* WT   = (unsigned short*)alloc((size_t)N3H * NE * 2);
  float*          UT   = (float*)alloc((size_t)N3H * NH * 4);
  unsigned short* xwb  = (unsigned short*)alloc((size_t)NM * N3H * 2);
  unsigned short* WdT  = (unsigned short*)alloc((size_t)NV * NH * 2);
  unsigned int*   Hex  = (unsigned int*)alloc((size_t)257 * 4096 * 4);

  hipMemsetAsync(Hex, 0xFF, (size_t)257 * 4096 * 4, stream);

  prep_kernel<<<18176, 256, 0, stream>>>(x, E, W, U, Wd, Aemb, WT, UT, WdT);

  gemm_bt<true><<<dim3(N3H / 128, NM / 128), 256, 0, stream>>>(Aemb, WT, bv, xwb, N3H, NE);

  gru_kernel<<<64, 256, 0, stream>>>(xwb, UT, bv, Hex);

  dec_gemm<<<8000, 256, 0, stream>>>((const char*)Hex, WdT, bd, out);
}